// Round 5
// baseline (1459.577 us; speedup 1.0000x reference)
//
#include <hip/hip_runtime.h>

#define HW 96
#define NPIX 9216      // 96*96
#define NCH 128
#define NB 16
#define HP 98          // haloed plane dim (coords -1..96)

// ---------------- channel mix: mixed[b,c,p] = sum_i lin[c,i] * x[b,i,p] ----------------
// R10: LDS-staged GEMM. Geometry = R5's measured-best (block 512 thr, tile
// 128 px x 128 ch, grid 72x16 = 1152; x-read redundancy R=1 -> fetch ~40MB,
// vs R9's 4-way ch-split at 156MB). NEW: x consumed via double-buffered LDS
// chunks [16 k x 128 px] with issue-early/write-late staging: next chunk's 4
// global loads issue BEFORE the 512-FMA compute block, ds_write lands AFTER
// (vmcnt drains under compute, T14). Inner loop reads x via ds_read_b64
// (~120cy, 2-way bank alias = free) in 4-k sub-batches (xv[4] float2 keeps
// VGPR ~56 -> 8 waves/SIMD).
// WHY: R5/R7/R9 post-mortems show per-wave issue duty ~45-56% at ANY occupancy
// (6 or 8 waves/SIMD) -- every wave convoys on s_waitcnt vmcnt(0) for its own
// strided global loads each k-batch; TLP can't cover ~600-900cy latency that
// sits on EVERY wave's critical path. Staging moves the global latency off
// the critical path entirely. R6 lesson stands: no manual vmcnt games; the
// pipelining here is structural (buffer parity), not instruction-level.
template<int K>
__global__ __launch_bounds__(512, 8) void mix_kernel(const float* __restrict__ x,
                                                     const float* __restrict__ lin,
                                                     float* __restrict__ mixed) {
    const int b    = blockIdx.y;
    const int px0  = blockIdx.x * 128;
    const int t    = threadIdx.x;
    const int lane = t & 63;
    const int c0   = __builtin_amdgcn_readfirstlane((t >> 6) * 16);
    const float* xb = x + (size_t)b * K * NPIX + px0;
    const float* lr = lin + c0 * K;

    __shared__ float xs[2][16 * 128];      // 16 KB double-buffered x chunk

    float2 acc[16];
    #pragma unroll
    for (int c = 0; c < 16; ++c) acc[c] = float2{0.f, 0.f};

    float st[4];
    // prologue: stage chunk 0 (k = 0..15)
    #pragma unroll
    for (int i = 0; i < 4; ++i) {
        const int idx = i * 512 + t;
        st[i] = xb[(size_t)(idx >> 7) * NPIX + (idx & 127)];
    }
    #pragma unroll
    for (int i = 0; i < 4; ++i) xs[0][i * 512 + t] = st[i];
    __syncthreads();

    const int NC = K / 16;
    for (int ci = 0; ci < NC; ++ci) {
        const int cur = ci & 1;
        // issue next chunk's global loads (latency hides under the FMA block)
        if (ci + 1 < NC) {
            #pragma unroll
            for (int i = 0; i < 4; ++i) {
                const int idx = i * 512 + t;
                st[i] = xb[(size_t)((ci + 1) * 16 + (idx >> 7)) * NPIX + (idx & 127)];
            }
        }
        // compute on current buffer: 4-k sub-batches, x from LDS, lin from SMEM
        const float* xc = xs[cur];
        #pragma unroll
        for (int ks = 0; ks < 16; ks += 4) {
            float2 xv[4];
            #pragma unroll
            for (int j = 0; j < 4; ++j)
                xv[j] = *(const float2*)&xc[(ks + j) * 128 + 2 * lane];
            #pragma unroll
            for (int c = 0; c < 16; ++c) {
                const float* lc = lr + c * K + ci * 16 + ks;   // wave-uniform -> s_load
                #pragma unroll
                for (int j = 0; j < 4; ++j) {
                    acc[c].x = fmaf(lc[j], xv[j].x, acc[c].x);
                    acc[c].y = fmaf(lc[j], xv[j].y, acc[c].y);
                }
            }
        }
        // write-late: ds_write next chunk (vmcnt already drained under compute)
        if (ci + 1 < NC) {
            float* xn = xs[cur ^ 1];
            #pragma unroll
            for (int i = 0; i < 4; ++i) xn[i * 512 + t] = st[i];
        }
        __syncthreads();
    }

    float* ob = mixed + (size_t)b * NCH * NPIX + px0;
    #pragma unroll
    for (int c = 0; c < 16; ++c)
        *(float2*)&ob[(size_t)(c0 + c) * NPIX + 2 * lane] = acc[c];
}

__device__ inline float clamp01(float z) { return fminf(fmaxf(z, 0.f), 1.f); }

// ---------------- bilinear affine sample (zero-halo LDS plane) ----------------
// Plane staged into LDS with a 1px zero border (coords -1..96). ix clamped to
// [-1,96]: every out-of-range tap then reads a zero cell with the correct
// weight, eliminating all validity masks. Box-sample-of-ones factorizes:
// bw = min(clamp01(bx+1), clamp01(96-bx)) * (same in y). 2-lerp form = 6 FMA.
// 512 threads: LDS (38.4 KB) allows 4 blocks/CU -> 32 waves/CU.
template<bool RES, bool POOL>
__global__ __launch_bounds__(512) void sample_kernel(const float* __restrict__ mixed,
                                                     const float* __restrict__ geo,
                                                     const float* __restrict__ box,
                                                     float* __restrict__ out,
                                                     float* __restrict__ pooled) {
    __shared__ float m[HP * HP];           // 38.4 KB -> 4 blocks/CU, 32 waves/CU
    const int c = blockIdx.x;
    const int b = blockIdx.y;
    const int t = threadIdx.x;
    // zero only the halo border (interior is fully overwritten by the fill)
    if (t < HP) {                           // top & bottom rows
        m[t] = 0.f;
        m[(HP - 1) * HP + t] = 0.f;
    } else if (t < HP + 96) {               // left & right columns (rows 1..96)
        const int h = t - HP + 1;
        m[h * HP] = 0.f;
        m[h * HP + HP - 1] = 0.f;
    }
    const float* src = mixed + ((size_t)b * NCH + c) * NPIX;
    #pragma unroll
    for (int r = 0; r < NPIX / 512; ++r) {
        const int idx = r * 512 + t;
        const int h = idx / 96, w = idx - (idx / 96) * 96;
        m[(h + 1) * HP + (w + 1)] = src[idx];
    }
    const float* gth = geo + c * 6;
    const float* bth = box + c * 6;
    const float g0 = gth[0], g1 = gth[1], g3 = gth[3], g4 = gth[4];
    const float gcx = 48.f * gth[2] - 47.5f * (g0 + g1) + 47.5f;
    const float gcy = 48.f * gth[5] - 47.5f * (g3 + g4) + 47.5f;
    const float b0 = bth[0], b1 = bth[1], b3 = bth[3], b4 = bth[4];
    const float bcx = 48.f * bth[2] - 47.5f * (b0 + b1) + 47.5f;
    const float bcy = 48.f * bth[5] - 47.5f * (b3 + b4) + 47.5f;
    float* o = out + ((size_t)b * NCH + c) * NPIX;
    __syncthreads();
    float psum = 0.f;
    #pragma unroll 6
    for (int r = 0; r < NPIX / 512; ++r) {
        const int p = r * 512 + t;
        const int h = p / 96, w = p - (p / 96) * 96;
        const float fw = (float)w, fh = (float)h;
        float ix = fmaf(g0, fw, fmaf(g1, fh, gcx));
        float iy = fmaf(g3, fw, fmaf(g4, fh, gcy));
        ix = fminf(fmaxf(ix, -1.f), 96.f);
        iy = fminf(fmaxf(iy, -1.f), 96.f);
        const float x0f = floorf(ix), y0f = floorf(iy);
        const float fx = ix - x0f, fy = iy - y0f;
        const int base = ((int)y0f + 1) * HP + ((int)x0f + 1);
        const float m00 = m[base],      m01 = m[base + 1];
        const float m10 = m[base + HP], m11 = m[base + HP + 1];
        const float mx0 = fmaf(fx, m01 - m00, m00);
        const float mx1 = fmaf(fx, m11 - m10, m10);
        float v = fmaf(fy, mx1 - mx0, mx0);
        const float bx = fmaf(b0, fw, fmaf(b1, fh, bcx));
        const float by = fmaf(b3, fw, fmaf(b4, fh, bcy));
        const float Xs = fminf(clamp01(bx + 1.f), clamp01(96.f - bx));
        const float Ys = fminf(clamp01(by + 1.f), clamp01(96.f - by));
        v *= Xs * Ys;
        if (RES) v += o[p];
        o[p] = v;
        if (POOL) psum += v;
    }
    if (POOL) {
        #pragma unroll
        for (int off = 32; off > 0; off >>= 1) psum += __shfl_down(psum, off, 64);
        __shared__ float red[8];
        if ((t & 63) == 0) red[t >> 6] = psum;
        __syncthreads();
        if (t == 0) {
            float s = 0.f;
            #pragma unroll
            for (int i = 0; i < 8; ++i) s += red[i];
            pooled[b * NCH + c] = s * (1.f / (float)NPIX);
        }
    }
}

// ---------------- mean pool (fallback when ws has no room for pooled) ----------------
__global__ __launch_bounds__(256) void pool_kernel(const float* __restrict__ feat,
                                                   float* __restrict__ pooled) {
    const int bc = blockIdx.x;           // b*128 + c
    const float4* f = (const float4*)(feat + (size_t)bc * NPIX);
    float s = 0.f;
    for (int i = threadIdx.x; i < NPIX / 4; i += 256) {
        const float4 v = f[i];
        s += (v.x + v.y) + (v.z + v.w);
    }
    #pragma unroll
    for (int off = 32; off > 0; off >>= 1) s += __shfl_down(s, off, 64);
    __shared__ float red[4];
    if ((threadIdx.x & 63) == 0) red[threadIdx.x >> 6] = s;
    __syncthreads();
    if (threadIdx.x == 0)
        pooled[bc] = (red[0] + red[1] + red[2] + red[3]) * (1.f / (float)NPIX);
}

// ---------------- dense: logits[b,n] = pooled[b,:] . W[n,:] + bias[n] ----------------
__global__ __launch_bounds__(256) void dense_kernel(const float* __restrict__ pooled,
                                                    const float* __restrict__ Wt,
                                                    const float* __restrict__ bias,
                                                    float* __restrict__ out) {
    const int idx = blockIdx.x * 256 + threadIdx.x;
    if (idx >= NB * 1000) return;
    const int b = idx / 1000, n = idx - b * 1000;
    float acc = bias[n];
    const float* p = pooled + b * NCH;
    const float* wr = Wt + n * NCH;
    #pragma unroll 4
    for (int c = 0; c < NCH; ++c) acc = fmaf(p[c], wr[c], acc);
    out[idx] = acc;
}

extern "C" void kernel_launch(void* const* d_in, const int* in_sizes, int n_in,
                              void* d_out, int out_size, void* d_ws, size_t ws_size,
                              hipStream_t stream) {
    const float* x       = (const float*)d_in[0];   // [16,64,96,96]
    const float* in_geo  = (const float*)d_in[1];   // [128,2,3]
    const float* in_box  = (const float*)d_in[2];   // [128,2,3]
    const float* in_lin  = (const float*)d_in[3];   // [128,64]
    const float* lay_geo = (const float*)d_in[4];   // [4,128,2,3]
    const float* lay_box = (const float*)d_in[5];   // [4,128,2,3]
    const float* lay_lin = (const float*)d_in[6];   // [4,128,128]
    const float* dense_w = (const float*)d_in[7];   // [1000,128]
    const float* dense_b = (const float*)d_in[8];   // [1000]

    float* out  = (float*)d_out;
    float* feat = out + NB * 1000;                  // [16,128,96,96] lives in d_out
    float* mixed = (float*)d_ws;                    // 75.5 MB scratch

    const size_t mixedFloats = (size_t)NB * NCH * NPIX;
    const bool fusedPool = ws_size >= (mixedFloats + NB * NCH) * sizeof(float);
    float* pooled = fusedPool ? (float*)d_ws + mixedFloats : (float*)d_ws;

    const dim3 mixGrid(NPIX / 128, NB);             // 72 x 16 = 1152 blocks of 512
    const dim3 smpGrid(NCH, NB);

    mix_kernel<64><<<mixGrid, 512, 0, stream>>>(x, in_lin, mixed);
    sample_kernel<false, false><<<smpGrid, 512, 0, stream>>>(mixed, in_geo, in_box, feat, pooled);
    for (int i = 0; i < 3; ++i) {
        mix_kernel<128><<<mixGrid, 512, 0, stream>>>(feat, lay_lin + i * NCH * NCH, mixed);
        sample_kernel<true, false><<<smpGrid, 512, 0, stream>>>(mixed, lay_geo + i * NCH * 6,
                                                                lay_box + i * NCH * 6, feat, pooled);
    }
    mix_kernel<128><<<mixGrid, 512, 0, stream>>>(feat, lay_lin + 3 * NCH * NCH, mixed);
    if (fusedPool) {
        sample_kernel<true, true><<<smpGrid, 512, 0, stream>>>(mixed, lay_geo + 3 * NCH * 6,
                                                               lay_box + 3 * NCH * 6, feat, pooled);
    } else {
        sample_kernel<true, false><<<smpGrid, 512, 0, stream>>>(mixed, lay_geo + 3 * NCH * 6,
                                                                lay_box + 3 * NCH * 6, feat, pooled);
        pool_kernel<<<NB * NCH, 256, 0, stream>>>(feat, pooled);
    }
    dense_kernel<<<(NB * 1000 + 255) / 256, 256, 0, stream>>>(pooled, dense_w, dense_b, out);
}

// Round 6
// 740.181 us; speedup vs baseline: 1.9719x; 1.9719x over previous
//
#include <hip/hip_runtime.h>

#define HW 96
#define NPIX 9216      // 96*96
#define NCH 128
#define NB 16
#define HP 98          // haloed plane dim (coords -1..96)

// ---------------- channel mix: mixed[b,c,p] = sum_i lin[c,i] * x[b,i,p] ----------------
// R11 = R10's LDS-staged GEMM with the spill fixed. Geometry = R5's measured-best
// (block 512 thr, tile 128 px x 128 ch, grid 72x16 = 1152, x redundancy R=1).
// x consumed via double-buffered LDS chunks [16 k x 128 px], issue-early/
// write-late (T14): next chunk's global_load_dwordx4 issues BEFORE the 512-FMA
// compute block, ds_write_b128 lands AFTER (vmcnt drains under ~1024cy of FMA).
// Inner loop reads x via ds_read_b64 (2-way bank alias = free).
// WHY (R5 arithmetic): per 8-k batch R5 does 8 loads -> vmcnt(0) -> 512cy FMA;
// with ~400cy L3 latency un-pipelined on every batch, duty = 512/912 = 56% --
// matches measured VALU 51%. Staging removes that latency from the critical path.
// R10 POST-MORTEM: __launch_bounds__(512,8) forced a 64-VGPR cap -> acc spilled
// to scratch -> 571MB WRITE_SIZE (vs 73MB output) and 283us. Fix: lb(512,4)
// (128-VGPR cap; ~60-70 used, no spill). Residency unchanged: 8 waves/block
// caps at 4 blocks/CU = 32 waves/CU regardless.
template<int K>
__global__ __launch_bounds__(512, 4) void mix_kernel(const float* __restrict__ x,
                                                     const float* __restrict__ lin,
                                                     float* __restrict__ mixed) {
    const int b    = blockIdx.y;
    const int px0  = blockIdx.x * 128;
    const int t    = threadIdx.x;
    const int lane = t & 63;
    const int c0   = __builtin_amdgcn_readfirstlane((t >> 6) * 16);
    const float* xb = x + (size_t)b * K * NPIX + px0;
    const float* lr = lin + c0 * K;

    __shared__ float xs[2][16 * 128];      // 16 KB double-buffered x chunk

    float2 acc[16];
    #pragma unroll
    for (int c = 0; c < 16; ++c) acc[c] = float2{0.f, 0.f};

    // stage-load mapping: thread t covers chunk row t>>5 (0..15), cols (t&31)*4..+3
    const int srow = t >> 5, scol = (t & 31) * 4;

    // prologue: stage chunk 0 (k = 0..15)
    float4 st = *(const float4*)&xb[(size_t)srow * NPIX + scol];
    *(float4*)&xs[0][t * 4] = st;          // xs row srow, col scol  (t*4 == srow*128+scol)
    __syncthreads();

    const int NC = K / 16;
    for (int ci = 0; ci < NC; ++ci) {
        const int cur = ci & 1;
        // issue next chunk's global load early (latency hides under the FMA block)
        if (ci + 1 < NC)
            st = *(const float4*)&xb[(size_t)((ci + 1) * 16 + srow) * NPIX + scol];
        // compute on current buffer: 4-k sub-batches, x from LDS, lin wave-uniform
        const float* xc = xs[cur];
        #pragma unroll
        for (int ks = 0; ks < 16; ks += 4) {
            float2 xv[4];
            #pragma unroll
            for (int j = 0; j < 4; ++j)
                xv[j] = *(const float2*)&xc[(ks + j) * 128 + 2 * lane];
            #pragma unroll
            for (int c = 0; c < 16; ++c) {
                const float* lc = lr + c * K + ci * 16 + ks;   // wave-uniform -> s_load
                #pragma unroll
                for (int j = 0; j < 4; ++j) {
                    acc[c].x = fmaf(lc[j], xv[j].x, acc[c].x);
                    acc[c].y = fmaf(lc[j], xv[j].y, acc[c].y);
                }
            }
        }
        // write-late: ds_write next chunk (vmcnt already drained under compute)
        if (ci + 1 < NC) {
            *(float4*)&xs[cur ^ 1][t * 4] = st;
            __syncthreads();
        }
    }

    float* ob = mixed + (size_t)b * NCH * NPIX + px0;
    #pragma unroll
    for (int c = 0; c < 16; ++c)
        *(float2*)&ob[(size_t)(c0 + c) * NPIX + 2 * lane] = acc[c];
}

__device__ inline float clamp01(float z) { return fminf(fmaxf(z, 0.f), 1.f); }

// ---------------- bilinear affine sample (zero-halo LDS plane) ----------------
// Plane staged into LDS with a 1px zero border (coords -1..96). ix clamped to
// [-1,96]: every out-of-range tap then reads a zero cell with the correct
// weight, eliminating all validity masks. Box-sample-of-ones factorizes:
// bw = min(clamp01(bx+1), clamp01(96-bx)) * (same in y). 2-lerp form = 6 FMA.
// 512 threads: LDS (38.4 KB) allows 4 blocks/CU -> 32 waves/CU (R6: helped ~39us).
template<bool RES, bool POOL>
__global__ __launch_bounds__(512) void sample_kernel(const float* __restrict__ mixed,
                                                     const float* __restrict__ geo,
                                                     const float* __restrict__ box,
                                                     float* __restrict__ out,
                                                     float* __restrict__ pooled) {
    __shared__ float m[HP * HP];           // 38.4 KB -> 4 blocks/CU, 32 waves/CU
    const int c = blockIdx.x;
    const int b = blockIdx.y;
    const int t = threadIdx.x;
    // zero only the halo border (interior is fully overwritten by the fill)
    if (t < HP) {                           // top & bottom rows
        m[t] = 0.f;
        m[(HP - 1) * HP + t] = 0.f;
    } else if (t < HP + 96) {               // left & right columns (rows 1..96)
        const int h = t - HP + 1;
        m[h * HP] = 0.f;
        m[h * HP + HP - 1] = 0.f;
    }
    const float* src = mixed + ((size_t)b * NCH + c) * NPIX;
    #pragma unroll
    for (int r = 0; r < NPIX / 512; ++r) {
        const int idx = r * 512 + t;
        const int h = idx / 96, w = idx - (idx / 96) * 96;
        m[(h + 1) * HP + (w + 1)] = src[idx];
    }
    const float* gth = geo + c * 6;
    const float* bth = box + c * 6;
    const float g0 = gth[0], g1 = gth[1], g3 = gth[3], g4 = gth[4];
    const float gcx = 48.f * gth[2] - 47.5f * (g0 + g1) + 47.5f;
    const float gcy = 48.f * gth[5] - 47.5f * (g3 + g4) + 47.5f;
    const float b0 = bth[0], b1 = bth[1], b3 = bth[3], b4 = bth[4];
    const float bcx = 48.f * bth[2] - 47.5f * (b0 + b1) + 47.5f;
    const float bcy = 48.f * bth[5] - 47.5f * (b3 + b4) + 47.5f;
    float* o = out + ((size_t)b * NCH + c) * NPIX;
    __syncthreads();
    float psum = 0.f;
    #pragma unroll 6
    for (int r = 0; r < NPIX / 512; ++r) {
        const int p = r * 512 + t;
        const int h = p / 96, w = p - (p / 96) * 96;
        const float fw = (float)w, fh = (float)h;
        float ix = fmaf(g0, fw, fmaf(g1, fh, gcx));
        float iy = fmaf(g3, fw, fmaf(g4, fh, gcy));
        ix = fminf(fmaxf(ix, -1.f), 96.f);
        iy = fminf(fmaxf(iy, -1.f), 96.f);
        const float x0f = floorf(ix), y0f = floorf(iy);
        const float fx = ix - x0f, fy = iy - y0f;
        const int base = ((int)y0f + 1) * HP + ((int)x0f + 1);
        const float m00 = m[base],      m01 = m[base + 1];
        const float m10 = m[base + HP], m11 = m[base + HP + 1];
        const float mx0 = fmaf(fx, m01 - m00, m00);
        const float mx1 = fmaf(fx, m11 - m10, m10);
        float v = fmaf(fy, mx1 - mx0, mx0);
        const float bx = fmaf(b0, fw, fmaf(b1, fh, bcx));
        const float by = fmaf(b3, fw, fmaf(b4, fh, bcy));
        const float Xs = fminf(clamp01(bx + 1.f), clamp01(96.f - bx));
        const float Ys = fminf(clamp01(by + 1.f), clamp01(96.f - by));
        v *= Xs * Ys;
        if (RES) v += o[p];
        o[p] = v;
        if (POOL) psum += v;
    }
    if (POOL) {
        #pragma unroll
        for (int off = 32; off > 0; off >>= 1) psum += __shfl_down(psum, off, 64);
        __shared__ float red[8];
        if ((t & 63) == 0) red[t >> 6] = psum;
        __syncthreads();
        if (t == 0) {
            float s = 0.f;
            #pragma unroll
            for (int i = 0; i < 8; ++i) s += red[i];
            pooled[b * NCH + c] = s * (1.f / (float)NPIX);
        }
    }
}

// ---------------- mean pool (fallback when ws has no room for pooled) ----------------
__global__ __launch_bounds__(256) void pool_kernel(const float* __restrict__ feat,
                                                   float* __restrict__ pooled) {
    const int bc = blockIdx.x;           // b*128 + c
    const float4* f = (const float4*)(feat + (size_t)bc * NPIX);
    float s = 0.f;
    for (int i = threadIdx.x; i < NPIX / 4; i += 256) {
        const float4 v = f[i];
        s += (v.x + v.y) + (v.z + v.w);
    }
    #pragma unroll
    for (int off = 32; off > 0; off >>= 1) s += __shfl_down(s, off, 64);
    __shared__ float red[4];
    if ((threadIdx.x & 63) == 0) red[threadIdx.x >> 6] = s;
    __syncthreads();
    if (threadIdx.x == 0)
        pooled[bc] = (red[0] + red[1] + red[2] + red[3]) * (1.f / (float)NPIX);
}

// ---------------- dense: logits[b,n] = pooled[b,:] . W[n,:] + bias[n] ----------------
__global__ __launch_bounds__(256) void dense_kernel(const float* __restrict__ pooled,
                                                    const float* __restrict__ Wt,
                                                    const float* __restrict__ bias,
                                                    float* __restrict__ out) {
    const int idx = blockIdx.x * 256 + threadIdx.x;
    if (idx >= NB * 1000) return;
    const int b = idx / 1000, n = idx - b * 1000;
    float acc = bias[n];
    const float* p = pooled + b * NCH;
    const float* wr = Wt + n * NCH;
    #pragma unroll 4
    for (int c = 0; c < NCH; ++c) acc = fmaf(p[c], wr[c], acc);
    out[idx] = acc;
}

extern "C" void kernel_launch(void* const* d_in, const int* in_sizes, int n_in,
                              void* d_out, int out_size, void* d_ws, size_t ws_size,
                              hipStream_t stream) {
    const float* x       = (const float*)d_in[0];   // [16,64,96,96]
    const float* in_geo  = (const float*)d_in[1];   // [128,2,3]
    const float* in_box  = (const float*)d_in[2];   // [128,2,3]
    const float* in_lin  = (const float*)d_in[3];   // [128,64]
    const float* lay_geo = (const float*)d_in[4];   // [4,128,2,3]
    const float* lay_box = (const float*)d_in[5];   // [4,128,2,3]
    const float* lay_lin = (const float*)d_in[6];   // [4,128,128]
    const float* dense_w = (const float*)d_in[7];   // [1000,128]
    const float* dense_b = (const float*)d_in[8];   // [1000]

    float* out  = (float*)d_out;
    float* feat = out + NB * 1000;                  // [16,128,96,96] lives in d_out
    float* mixed = (float*)d_ws;                    // 75.5 MB scratch

    const size_t mixedFloats = (size_t)NB * NCH * NPIX;
    const bool fusedPool = ws_size >= (mixedFloats + NB * NCH) * sizeof(float);
    float* pooled = fusedPool ? (float*)d_ws + mixedFloats : (float*)d_ws;

    const dim3 mixGrid(NPIX / 128, NB);             // 72 x 16 = 1152 blocks of 512
    const dim3 smpGrid(NCH, NB);

    mix_kernel<64><<<mixGrid, 512, 0, stream>>>(x, in_lin, mixed);
    sample_kernel<false, false><<<smpGrid, 512, 0, stream>>>(mixed, in_geo, in_box, feat, pooled);
    for (int i = 0; i < 3; ++i) {
        mix_kernel<128><<<mixGrid, 512, 0, stream>>>(feat, lay_lin + i * NCH * NCH, mixed);
        sample_kernel<true, false><<<smpGrid, 512, 0, stream>>>(mixed, lay_geo + i * NCH * 6,
                                                                lay_box + i * NCH * 6, feat, pooled);
    }
    mix_kernel<128><<<mixGrid, 512, 0, stream>>>(feat, lay_lin + 3 * NCH * NCH, mixed);
    if (fusedPool) {
        sample_kernel<true, true><<<smpGrid, 512, 0, stream>>>(mixed, lay_geo + 3 * NCH * 6,
                                                               lay_box + 3 * NCH * 6, feat, pooled);
    } else {
        sample_kernel<true, false><<<smpGrid, 512, 0, stream>>>(mixed, lay_geo + 3 * NCH * 6,
                                                                lay_box + 3 * NCH * 6, feat, pooled);
        pool_kernel<<<NB * NCH, 256, 0, stream>>>(feat, pooled);
    }
    dense_kernel<<<(NB * 1000 + 255) / 256, 256, 0, stream>>>(pooled, dense_w, dense_b, out);
}

// Round 7
// 564.993 us; speedup vs baseline: 2.5834x; 1.3101x over previous
//
#include <hip/hip_runtime.h>

#define HW 96
#define NPIX 9216      // 96*96
#define NCH 128
#define NB 16
#define HP 98          // haloed plane dim (coords -1..96)

// ---------------- channel mix: mixed[b,c,p] = sum_i lin[c,i] * x[b,i,p] ----------------
// R12 = R5's measured-best structure (no-LDS, block 512 thr, tile 128px x 128ch,
// grid 72x16, wave = 16 ch, lin wave-uniform s_load = the 1 SGPR operand of
// v_fma) with ONE change: k-batch depth 8 -> 16.
// WHY: R5 duty model: per batch C=512 SIMD-cy of FMA + un-hidden stall L~490cy
// (51% VALU measured). L is paid per batch; C scales with depth. Depth 16 ->
// duty 1024/(1024+490) ~ 68% -> ~53us. xv[16] float2 = 32 VGPR, acc 32,
// total ~80; lb(512,4) = 128-VGPR cap (R10 lesson: lb(512,8)'s 64-cap spilled).
// Occupancy unchanged: 512-thr blocks cap at 4 blocks/CU = 32 waves/CU.
// DEAD ENDS (measured): R6 manual ping-pong 92us; R9 ch-split 4x fetch 96us;
// R10 LDS-staged spill 283us; R11 LDS-staged clean 129us (ds_read + s_load
// share lgkmcnt -> conservative lgkmcnt(0) serializes every sub-batch).
template<int K>
__global__ __launch_bounds__(512, 4) void mix_kernel(const float* __restrict__ x,
                                                     const float* __restrict__ lin,
                                                     float* __restrict__ mixed) {
    const int b    = blockIdx.y;
    const int lane = threadIdx.x & 63;
    const int p    = blockIdx.x * 128 + lane * 2;
    const int c0   = __builtin_amdgcn_readfirstlane((threadIdx.x >> 6) * 16);
    const float* xb = x + (size_t)b * K * NPIX + p;
    const float* lr = lin + c0 * K;

    float2 acc[16];
    #pragma unroll
    for (int c = 0; c < 16; ++c) acc[c] = float2{0.f, 0.f};

    for (int k0 = 0; k0 < K; k0 += 16) {
        float2 xv[16];
        #pragma unroll
        for (int j = 0; j < 16; ++j)
            xv[j] = *(const float2*)&xb[(size_t)(k0 + j) * NPIX];
        #pragma unroll
        for (int c = 0; c < 16; ++c) {
            const float* lc = lr + c * K + k0;     // wave-uniform -> s_load
            #pragma unroll
            for (int j = 0; j < 16; ++j) {
                acc[c].x = fmaf(lc[j], xv[j].x, acc[c].x);
                acc[c].y = fmaf(lc[j], xv[j].y, acc[c].y);
            }
        }
    }
    float* ob = mixed + (size_t)b * NCH * NPIX + p;
    #pragma unroll
    for (int c = 0; c < 16; ++c)
        *(float2*)&ob[(size_t)(c0 + c) * NPIX] = acc[c];
}

__device__ inline float clamp01(float z) { return fminf(fmaxf(z, 0.f), 1.f); }

// ---------------- bilinear affine sample (zero-halo LDS plane) ----------------
// Plane staged into LDS with a 1px zero border (coords -1..96). ix clamped to
// [-1,96]: every out-of-range tap then reads a zero cell with the correct
// weight, eliminating all validity masks. Box-sample-of-ones factorizes:
// bw = min(clamp01(bx+1), clamp01(96-bx)) * (same in y). 2-lerp form = 6 FMA.
// 512 threads (R6 evidence: helped): LDS 38.4 KB -> 4 blocks/CU, 32 waves/CU.
template<bool RES, bool POOL>
__global__ __launch_bounds__(512) void sample_kernel(const float* __restrict__ mixed,
                                                     const float* __restrict__ geo,
                                                     const float* __restrict__ box,
                                                     float* __restrict__ out,
                                                     float* __restrict__ pooled) {
    __shared__ float m[HP * HP];           // 38.4 KB -> 4 blocks/CU, 32 waves/CU
    const int c = blockIdx.x;
    const int b = blockIdx.y;
    const int t = threadIdx.x;
    // zero only the halo border (interior is fully overwritten by the fill)
    if (t < HP) {                           // top & bottom rows
        m[t] = 0.f;
        m[(HP - 1) * HP + t] = 0.f;
    } else if (t < HP + 96) {               // left & right columns (rows 1..96)
        const int h = t - HP + 1;
        m[h * HP] = 0.f;
        m[h * HP + HP - 1] = 0.f;
    }
    const float* src = mixed + ((size_t)b * NCH + c) * NPIX;
    #pragma unroll
    for (int r = 0; r < NPIX / 512; ++r) {
        const int idx = r * 512 + t;
        const int h = idx / 96, w = idx - (idx / 96) * 96;
        m[(h + 1) * HP + (w + 1)] = src[idx];
    }
    const float* gth = geo + c * 6;
    const float* bth = box + c * 6;
    const float g0 = gth[0], g1 = gth[1], g3 = gth[3], g4 = gth[4];
    const float gcx = 48.f * gth[2] - 47.5f * (g0 + g1) + 47.5f;
    const float gcy = 48.f * gth[5] - 47.5f * (g3 + g4) + 47.5f;
    const float b0 = bth[0], b1 = bth[1], b3 = bth[3], b4 = bth[4];
    const float bcx = 48.f * bth[2] - 47.5f * (b0 + b1) + 47.5f;
    const float bcy = 48.f * bth[5] - 47.5f * (b3 + b4) + 47.5f;
    float* o = out + ((size_t)b * NCH + c) * NPIX;
    __syncthreads();
    float psum = 0.f;
    #pragma unroll 6
    for (int r = 0; r < NPIX / 512; ++r) {
        const int p = r * 512 + t;
        const int h = p / 96, w = p - (p / 96) * 96;
        const float fw = (float)w, fh = (float)h;
        float ix = fmaf(g0, fw, fmaf(g1, fh, gcx));
        float iy = fmaf(g3, fw, fmaf(g4, fh, gcy));
        ix = fminf(fmaxf(ix, -1.f), 96.f);
        iy = fminf(fmaxf(iy, -1.f), 96.f);
        const float x0f = floorf(ix), y0f = floorf(iy);
        const float fx = ix - x0f, fy = iy - y0f;
        const int base = ((int)y0f + 1) * HP + ((int)x0f + 1);
        const float m00 = m[base],      m01 = m[base + 1];
        const float m10 = m[base + HP], m11 = m[base + HP + 1];
        const float mx0 = fmaf(fx, m01 - m00, m00);
        const float mx1 = fmaf(fx, m11 - m10, m10);
        float v = fmaf(fy, mx1 - mx0, mx0);
        const float bx = fmaf(b0, fw, fmaf(b1, fh, bcx));
        const float by = fmaf(b3, fw, fmaf(b4, fh, bcy));
        const float Xs = fminf(clamp01(bx + 1.f), clamp01(96.f - bx));
        const float Ys = fminf(clamp01(by + 1.f), clamp01(96.f - by));
        v *= Xs * Ys;
        if (RES) v += o[p];
        o[p] = v;
        if (POOL) psum += v;
    }
    if (POOL) {
        #pragma unroll
        for (int off = 32; off > 0; off >>= 1) psum += __shfl_down(psum, off, 64);
        __shared__ float red[8];
        if ((t & 63) == 0) red[t >> 6] = psum;
        __syncthreads();
        if (t == 0) {
            float s = 0.f;
            #pragma unroll
            for (int i = 0; i < 8; ++i) s += red[i];
            pooled[b * NCH + c] = s * (1.f / (float)NPIX);
        }
    }
}

// ---------------- mean pool (fallback when ws has no room for pooled) ----------------
__global__ __launch_bounds__(256) void pool_kernel(const float* __restrict__ feat,
                                                   float* __restrict__ pooled) {
    const int bc = blockIdx.x;           // b*128 + c
    const float4* f = (const float4*)(feat + (size_t)bc * NPIX);
    float s = 0.f;
    for (int i = threadIdx.x; i < NPIX / 4; i += 256) {
        const float4 v = f[i];
        s += (v.x + v.y) + (v.z + v.w);
    }
    #pragma unroll
    for (int off = 32; off > 0; off >>= 1) s += __shfl_down(s, off, 64);
    __shared__ float red[4];
    if ((threadIdx.x & 63) == 0) red[threadIdx.x >> 6] = s;
    __syncthreads();
    if (threadIdx.x == 0)
        pooled[bc] = (red[0] + red[1] + red[2] + red[3]) * (1.f / (float)NPIX);
}

// ---------------- dense: logits[b,n] = pooled[b,:] . W[n,:] + bias[n] ----------------
__global__ __launch_bounds__(256) void dense_kernel(const float* __restrict__ pooled,
                                                    const float* __restrict__ Wt,
                                                    const float* __restrict__ bias,
                                                    float* __restrict__ out) {
    const int idx = blockIdx.x * 256 + threadIdx.x;
    if (idx >= NB * 1000) return;
    const int b = idx / 1000, n = idx - b * 1000;
    float acc = bias[n];
    const float* p = pooled + b * NCH;
    const float* wr = Wt + n * NCH;
    #pragma unroll 4
    for (int c = 0; c < NCH; ++c) acc = fmaf(p[c], wr[c], acc);
    out[idx] = acc;
}

extern "C" void kernel_launch(void* const* d_in, const int* in_sizes, int n_in,
                              void* d_out, int out_size, void* d_ws, size_t ws_size,
                              hipStream_t stream) {
    const float* x       = (const float*)d_in[0];   // [16,64,96,96]
    const float* in_geo  = (const float*)d_in[1];   // [128,2,3]
    const float* in_box  = (const float*)d_in[2];   // [128,2,3]
    const float* in_lin  = (const float*)d_in[3];   // [128,64]
    const float* lay_geo = (const float*)d_in[4];   // [4,128,2,3]
    const float* lay_box = (const float*)d_in[5];   // [4,128,2,3]
    const float* lay_lin = (const float*)d_in[6];   // [4,128,128]
    const float* dense_w = (const float*)d_in[7];   // [1000,128]
    const float* dense_b = (const float*)d_in[8];   // [1000]

    float* out  = (float*)d_out;
    float* feat = out + NB * 1000;                  // [16,128,96,96] lives in d_out
    float* mixed = (float*)d_ws;                    // 75.5 MB scratch

    const size_t mixedFloats = (size_t)NB * NCH * NPIX;
    const bool fusedPool = ws_size >= (mixedFloats + NB * NCH) * sizeof(float);
    float* pooled = fusedPool ? (float*)d_ws + mixedFloats : (float*)d_ws;

    const dim3 mixGrid(NPIX / 128, NB);             // 72 x 16 = 1152 blocks of 512
    const dim3 smpGrid(NCH, NB);

    mix_kernel<64><<<mixGrid, 512, 0, stream>>>(x, in_lin, mixed);
    sample_kernel<false, false><<<smpGrid, 512, 0, stream>>>(mixed, in_geo, in_box, feat, pooled);
    for (int i = 0; i < 3; ++i) {
        mix_kernel<128><<<mixGrid, 512, 0, stream>>>(feat, lay_lin + i * NCH * NCH, mixed);
        sample_kernel<true, false><<<smpGrid, 512, 0, stream>>>(mixed, lay_geo + i * NCH * 6,
                                                                lay_box + i * NCH * 6, feat, pooled);
    }
    mix_kernel<128><<<mixGrid, 512, 0, stream>>>(feat, lay_lin + 3 * NCH * NCH, mixed);
    if (fusedPool) {
        sample_kernel<true, true><<<smpGrid, 512, 0, stream>>>(mixed, lay_geo + 3 * NCH * 6,
                                                               lay_box + 3 * NCH * 6, feat, pooled);
    } else {
        sample_kernel<true, false><<<smpGrid, 512, 0, stream>>>(mixed, lay_geo + 3 * NCH * 6,
                                                                lay_box + 3 * NCH * 6, feat, pooled);
        pool_kernel<<<NB * NCH, 256, 0, stream>>>(feat, pooled);
    }
    dense_kernel<<<(NB * 1000 + 255) / 256, 256, 0, stream>>>(pooled, dense_w, dense_b, out);
}